// Round 6
// baseline (461.708 us; speedup 1.0000x reference)
//
#include <hip/hip_runtime.h>
#include <math.h>
#include <stdint.h>

// ScalarSGC: 2 layers of  x <- elu( scalars[l] * (A @ x) )
// CSR build (bucketed, zero global atomics; R4 showed direct random scatter is
// 7.7x write-amplified).  R6: per-edge atomic->store chains BATCHED x4 (int4
// edge loads, 4 independent LDS-atomic+store chains per iteration) to hide
// ~120cyc LDS-atomic latency that single chains can't.
// SpMM: 16-lane GROUP per row; lane owns 16B (8 bf16 features) of the row.
// Wave = 4 groups -> one gather instruction moves 4 x 256B = 1KB.
// pack[] loads are NON-TEMPORAL (streamed once; keeps gather table in L2).

#define D_FEAT 128
#define D2     64          // feature pairs per row
#define SCAN_TILE 1024

#define PB 256             // partition/count blocks (= gridDim of those kernels)
#define PT 1024            // threads per partition/count block
#define RB_BITS 9          // rows per bucket = 512
#define ROWS_PER_BUCKET 512
#define COL_BITS 17        // N = 100000 < 2^17
#define COL_MASK ((1 << COL_BITS) - 1)

__device__ __forceinline__ uint32_t f2bf(float f) {
    uint32_t u = __float_as_uint(f);
    return (u + 0x7FFFu + ((u >> 16) & 1u)) >> 16;   // RNE
}
__device__ __forceinline__ float bf_lo(uint32_t w) { return __uint_as_float(w << 16); }
__device__ __forceinline__ float bf_hi(uint32_t w) { return __uint_as_float(w & 0xFFFF0000u); }

// ------- fused: f32 -> bf16 table convert (float4) + coarse bucket count -------
__global__ __launch_bounds__(PT) void convert_count_kernel(const float4* __restrict__ xin,
                                                           uint2* __restrict__ xbf, int n4,
                                                           const int* __restrict__ row,
                                                           int* __restrict__ cnt,
                                                           int E, int nbuck) {
    __shared__ int hist[256];
    const int t = threadIdx.x;
    if (t < 256) hist[t] = 0;
    __syncthreads();
    const int stride = PB * PT;
    const int gid = blockIdx.x * PT + t;
    for (int i = gid; i < n4; i += stride) {
        float4 f = xin[i];
        xbf[i] = make_uint2(f2bf(f.x) | (f2bf(f.y) << 16),
                            f2bf(f.z) | (f2bf(f.w) << 16));
    }
    const int E4 = E >> 2;
    const int4* __restrict__ r4 = (const int4*)row;
    for (int i = gid; i < E4; i += stride) {
        int4 r = r4[i];
        atomicAdd(&hist[r.x >> RB_BITS], 1);
        atomicAdd(&hist[r.y >> RB_BITS], 1);
        atomicAdd(&hist[r.z >> RB_BITS], 1);
        atomicAdd(&hist[r.w >> RB_BITS], 1);
    }
    for (int i = (E4 << 2) + gid; i < E; i += stride)   // tail (E%4 != 0)
        atomicAdd(&hist[row[i] >> RB_BITS], 1);
    __syncthreads();
    if (t < nbuck) cnt[t * PB + blockIdx.x] = hist[t];
}

// ---------------- scan phase 1: per-tile exclusive scan + tile sums ----------------
__global__ __launch_bounds__(SCAN_TILE) void scan1_kernel(const int* __restrict__ counts,
                                                          int* __restrict__ excl,
                                                          int* __restrict__ tileSums, int n) {
    __shared__ int wsum[16];
    const int tid  = threadIdx.x;
    const int lane = tid & 63;
    const int wave = tid >> 6;
    const int i    = blockIdx.x * SCAN_TILE + tid;

    int v = (i < n) ? counts[i] : 0;
    int incl = v;
    #pragma unroll
    for (int off = 1; off < 64; off <<= 1) {
        int t = __shfl_up(incl, off, 64);
        if (lane >= off) incl += t;
    }
    if (lane == 63) wsum[wave] = incl;
    __syncthreads();
    if (wave == 0) {
        int s = (lane < 16) ? wsum[lane] : 0;
        #pragma unroll
        for (int off = 1; off < 16; off <<= 1) {
            int t = __shfl_up(s, off, 64);
            if (lane >= off) s += t;
        }
        if (lane < 16) wsum[lane] = s;
    }
    __syncthreads();
    int wbase = (wave == 0) ? 0 : wsum[wave - 1];
    if (i < n) excl[i] = wbase + (incl - v);
    if (tid == 0) tileSums[blockIdx.x] = wsum[15];
}

// ---------------- scan phase 2: single-wave shuffle scan of tile sums ----------------
__global__ __launch_bounds__(64) void scan2_kernel(const int* __restrict__ tileSums,
                                                   int* __restrict__ tileBase,
                                                   int* __restrict__ total_out, int nb) {
    const int lane = threadIdx.x;
    int v = (lane < nb) ? tileSums[lane] : 0;
    int incl = v;
    #pragma unroll
    for (int off = 1; off < 64; off <<= 1) {
        int t = __shfl_up(incl, off, 64);
        if (lane >= off) incl += t;
    }
    if (lane < nb) tileBase[lane] = incl - v;
    if (lane == nb - 1) *total_out = incl;
}

// ---------------- partition edges into coarse buckets (LDS cursors) ----------------
// 196 sequential write streams per block; 4 independent chains per iteration.
__global__ __launch_bounds__(PT) void partition_kernel(const int* __restrict__ row,
                                                       const int* __restrict__ col,
                                                       const float* __restrict__ val,
                                                       const int* __restrict__ cnt,
                                                       const int* __restrict__ tileBase,
                                                       int2* __restrict__ pack2,
                                                       int E, int nbuck) {
    __shared__ int cur[256];
    const int t = threadIdx.x;
    if (t < nbuck) {
        int idx = t * PB + blockIdx.x;
        cur[t] = cnt[idx] + tileBase[idx >> 10];
    }
    __syncthreads();
    const int stride = PB * PT;
    const int gid = blockIdx.x * PT + t;
    const int E4 = E >> 2;
    const int4*   __restrict__ r4 = (const int4*)row;
    const int4*   __restrict__ c4 = (const int4*)col;
    const float4* __restrict__ v4 = (const float4*)val;
    for (int i = gid; i < E4; i += stride) {
        int4   r = r4[i];
        int4   c = c4[i];
        float4 v = v4[i];
        int p0 = atomicAdd(&cur[r.x >> RB_BITS], 1);
        int p1 = atomicAdd(&cur[r.y >> RB_BITS], 1);
        int p2 = atomicAdd(&cur[r.z >> RB_BITS], 1);
        int p3 = atomicAdd(&cur[r.w >> RB_BITS], 1);
        pack2[p0] = make_int2(c.x | ((r.x & (ROWS_PER_BUCKET - 1)) << COL_BITS), __float_as_int(v.x));
        pack2[p1] = make_int2(c.y | ((r.y & (ROWS_PER_BUCKET - 1)) << COL_BITS), __float_as_int(v.y));
        pack2[p2] = make_int2(c.z | ((r.z & (ROWS_PER_BUCKET - 1)) << COL_BITS), __float_as_int(v.z));
        pack2[p3] = make_int2(c.w | ((r.w & (ROWS_PER_BUCKET - 1)) << COL_BITS), __float_as_int(v.w));
    }
    for (int i = (E4 << 2) + gid; i < E; i += stride) {  // tail
        int r = row[i];
        int pos = atomicAdd(&cur[r >> RB_BITS], 1);
        pack2[pos] = make_int2(col[i] | ((r & (ROWS_PER_BUCKET - 1)) << COL_BITS),
                               __float_as_int(val[i]));
    }
}

// ---------------- lean per-bucket fine sort (2 edges per int4 load) ----------------
__global__ __launch_bounds__(1024) void fine_sort_kernel(const int* __restrict__ cnt,
                                                         const int* __restrict__ tileBase,
                                                         const int2* __restrict__ pack2,
                                                         int2* __restrict__ pack,
                                                         int* __restrict__ offsets,
                                                         int E, int N, int nbuck) {
    __shared__ int hist[ROWS_PER_BUCKET];
    __shared__ int cur[ROWS_PER_BUCKET];
    __shared__ int wsum[8];
    const int b    = blockIdx.x;
    const int t    = threadIdx.x;
    const int wave = t >> 6;
    const int lane = t & 63;
    const int start = cnt[b << 8] + tileBase[b >> 2];
    const int end   = (b == nbuck - 1) ? E : (cnt[(b + 1) << 8] + tileBase[(b + 1) >> 2]);
    const int n = end - start;
    // int4 alignment: pack2+start is 16B-aligned iff start is even
    const int lead = (start & 1) & (n > 0 ? 1 : 0);
    const int base = start + lead;
    const int m  = n - lead;
    const int m2 = m >> 1;
    const int4* __restrict__ p4 = (const int4*)(pack2 + base);

    if (t < ROWS_PER_BUCKET) hist[t] = 0;
    __syncthreads();

    if (lead && t == 0) atomicAdd(&hist[((unsigned)pack2[start].x) >> COL_BITS], 1);
    for (int i = t; i < m2; i += 1024) {
        int4 w = p4[i];
        atomicAdd(&hist[((unsigned)w.x) >> COL_BITS], 1);
        atomicAdd(&hist[((unsigned)w.z) >> COL_BITS], 1);
    }
    if ((m & 1) && t == 0) atomicAdd(&hist[((unsigned)pack2[base + m - 1].x) >> COL_BITS], 1);
    __syncthreads();

    int v = 0, incl = 0;
    if (t < ROWS_PER_BUCKET) {           // waves 0..7, whole waves only
        v = hist[t];
        incl = v;
        #pragma unroll
        for (int off = 1; off < 64; off <<= 1) {
            int tv = __shfl_up(incl, off, 64);
            if (lane >= off) incl += tv;
        }
        if (lane == 63) wsum[wave] = incl;
    }
    __syncthreads();
    if (wave == 0) {                     // scan 8 wave sums
        int s = (lane < 8) ? wsum[lane] : 0;
        #pragma unroll
        for (int off = 1; off < 8; off <<= 1) {
            int tv = __shfl_up(s, off, 64);
            if (lane >= off) s += tv;
        }
        if (lane < 8) wsum[lane] = s;    // inclusive
    }
    __syncthreads();
    if (t < ROWS_PER_BUCKET) {
        int sbase = (wave == 0) ? 0 : wsum[wave - 1];
        int excl = sbase + incl - v;
        cur[t] = excl;
        int r = (b << RB_BITS) + t;
        if (r < N) offsets[r] = start + excl;
    }
    if (b == 0 && t == 0) offsets[N] = E;
    __syncthreads();

    if (lead && t == 0) {
        int2 w = pack2[start];
        int p = atomicAdd(&cur[((unsigned)w.x) >> COL_BITS], 1);
        pack[start + p] = make_int2(w.x & COL_MASK, w.y);
    }
    for (int i = t; i < m2; i += 1024) {
        int4 w = p4[i];
        int lr0 = ((unsigned)w.x) >> COL_BITS;
        int lr1 = ((unsigned)w.z) >> COL_BITS;
        int q0 = atomicAdd(&cur[lr0], 1);
        int q1 = atomicAdd(&cur[lr1], 1);
        pack[start + q0] = make_int2(w.x & COL_MASK, w.y);
        pack[start + q1] = make_int2(w.z & COL_MASK, w.w);
    }
    if ((m & 1) && t == 0) {
        int2 w = pack2[base + m - 1];
        int p = atomicAdd(&cur[((unsigned)w.x) >> COL_BITS], 1);
        pack[start + p] = make_int2(w.x & COL_MASK, w.y);
    }
}

// ---------------- fused SpMM (bf16 gather) + scalar scale + ELU ----------------
// Block = 256 threads = 16 groups of 16 lanes; GROUP owns one row.  Lane owns
// 16B (4 bf16-pair words = 8 features) of that row's accumulator.  A wave's
// gather instruction covers 4 groups x 256B = 1KB.  pack[] reads are
// group-uniform broadcasts, loaded NON-TEMPORAL (single-use stream; keeps the
// gather table resident in L2 instead).
template <int OUT_BF16>
__global__ __launch_bounds__(256) void spmm_elu_kernel(
    const int* __restrict__ offsets, const int2* __restrict__ pack,
    const uint32_t* __restrict__ xin, void* __restrict__ xout,
    const float* __restrict__ scalars, int layer, int N) {
    const int tid = threadIdx.x;
    const int grp = tid >> 4;            // group within block (0..15)
    const int sub = tid & 15;            // 16B chunk within the source row
    const int r   = blockIdx.x * 16 + grp;

    int e = 0, end = 0;
    if (r < N) { e = offsets[r]; end = offsets[r + 1]; }

    const uint4* __restrict__ xin4 = (const uint4*)xin;       // row stride = 16 uint4
    const uint64_t* __restrict__ pk = (const uint64_t*)pack;  // 8B per edge

    float a[8];
    #pragma unroll
    for (int k = 0; k < 8; ++k) a[k] = 0.f;

    #define FMA8(W, V)                                                     \
        a[0] += (V) * bf_lo((W).x); a[1] += (V) * bf_hi((W).x);            \
        a[2] += (V) * bf_lo((W).y); a[3] += (V) * bf_hi((W).y);            \
        a[4] += (V) * bf_lo((W).z); a[5] += (V) * bf_hi((W).z);            \
        a[6] += (V) * bf_lo((W).w); a[7] += (V) * bf_hi((W).w);

    for (; e + 4 <= end; e += 4) {
        uint64_t q0 = __builtin_nontemporal_load(&pk[e]);
        uint64_t q1 = __builtin_nontemporal_load(&pk[e + 1]);
        uint64_t q2 = __builtin_nontemporal_load(&pk[e + 2]);
        uint64_t q3 = __builtin_nontemporal_load(&pk[e + 3]);
        uint4 w0 = xin4[(((uint32_t)q0) << 4) + sub];
        uint4 w1 = xin4[(((uint32_t)q1) << 4) + sub];
        uint4 w2 = xin4[(((uint32_t)q2) << 4) + sub];
        uint4 w3 = xin4[(((uint32_t)q3) << 4) + sub];
        FMA8(w0, __uint_as_float((uint32_t)(q0 >> 32)));
        FMA8(w1, __uint_as_float((uint32_t)(q1 >> 32)));
        FMA8(w2, __uint_as_float((uint32_t)(q2 >> 32)));
        FMA8(w3, __uint_as_float((uint32_t)(q3 >> 32)));
    }
    for (; e < end; ++e) {
        uint64_t q = __builtin_nontemporal_load(&pk[e]);
        uint4 w = xin4[(((uint32_t)q) << 4) + sub];
        FMA8(w, __uint_as_float((uint32_t)(q >> 32)));
    }
    #undef FMA8

    const float s = scalars[layer];
    #pragma unroll
    for (int k = 0; k < 8; ++k) {
        float x = a[k] * s;
        a[k] = (x > 0.f) ? x : (expf(x) - 1.f);
    }

    if (r < N) {
        if (OUT_BF16) {
            uint4 o;
            o.x = f2bf(a[0]) | (f2bf(a[1]) << 16);
            o.y = f2bf(a[2]) | (f2bf(a[3]) << 16);
            o.z = f2bf(a[4]) | (f2bf(a[5]) << 16);
            o.w = f2bf(a[6]) | (f2bf(a[7]) << 16);
            ((uint4*)xout)[(size_t)r * 16 + sub] = o;
        } else {
            ((float4*)xout)[(size_t)r * 32 + sub * 2]     = make_float4(a[0], a[1], a[2], a[3]);
            ((float4*)xout)[(size_t)r * 32 + sub * 2 + 1] = make_float4(a[4], a[5], a[6], a[7]);
        }
    }
}

extern "C" void kernel_launch(void* const* d_in, const int* in_sizes, int n_in,
                              void* d_out, int out_size, void* d_ws, size_t ws_size,
                              hipStream_t stream) {
    const float* x         = (const float*)d_in[0];
    const int*   edge_row  = (const int*)d_in[1];
    const int*   edge_col  = (const int*)d_in[2];
    const float* edge_vals = (const float*)d_in[3];
    const float* scalars   = (const float*)d_in[4];

    const int N = in_sizes[0] / D_FEAT;                      // 100000
    const int E = in_sizes[1];                               // 3200000
    const int nbuck = (N + ROWS_PER_BUCKET - 1) >> RB_BITS;  // 196
    const int M = nbuck * PB;                                // 50176
    const int NB = (M + SCAN_TILE - 1) / SCAN_TILE;          // 49

    // ---- workspace bump allocator (256B aligned) ----
    char*  ws  = (char*)d_ws;
    size_t off = 0;
    auto alloc = [&](size_t bytes) -> void* {
        off = (off + 255) & ~(size_t)255;
        void* p = ws + off;
        off += bytes;
        return p;
    };
    int*      offsets  = (int*)alloc((size_t)(N + 1) * sizeof(int));
    int*      cnt      = (int*)alloc((size_t)(M + 1) * sizeof(int));
    int*      tileSums = (int*)alloc((size_t)NB * sizeof(int));
    int*      tileBase = (int*)alloc((size_t)NB * sizeof(int));
    int2*     pack2    = (int2*)alloc((size_t)E * sizeof(int2));
    int2*     pack     = (int2*)alloc((size_t)E * sizeof(int2));
    uint32_t* xbf      = (uint32_t*)alloc((size_t)N * D2 * sizeof(uint32_t));
    uint32_t* hbf      = (uint32_t*)pack2;   // alias: pack2 dead after fine_sort
    (void)ws_size;

    // ---- bf16 table + CSR build (no global atomics) ----
    convert_count_kernel<<<PB, PT, 0, stream>>>((const float4*)x, (uint2*)xbf, N * D2 / 2,
                                                edge_row, cnt, E, nbuck);
    scan1_kernel<<<NB, SCAN_TILE, 0, stream>>>(cnt, cnt, tileSums, M);
    scan2_kernel<<<1, 64, 0, stream>>>(tileSums, tileBase, cnt + M, NB);
    partition_kernel<<<PB, PT, 0, stream>>>(edge_row, edge_col, edge_vals, cnt, tileBase,
                                            pack2, E, nbuck);
    fine_sort_kernel<<<nbuck, 1024, 0, stream>>>(cnt, tileBase, pack2, pack, offsets, E, N, nbuck);

    // ---- layer 1: xbf -> hbf (bf16), layer 2: hbf -> d_out (f32) ----
    const int nblk = (N + 15) / 16;
    spmm_elu_kernel<1><<<nblk, 256, 0, stream>>>(offsets, pack, xbf, hbf, scalars, 0, N);
    spmm_elu_kernel<0><<<nblk, 256, 0, stream>>>(offsets, pack, hbf, (void*)d_out, scalars, 1, N);
}

// Round 8
// 428.933 us; speedup vs baseline: 1.0764x; 1.0764x over previous
//
#include <hip/hip_runtime.h>
#include <math.h>
#include <stdint.h>

// ScalarSGC: 2 layers of  x <- elu( scalars[l] * (A @ x) )
// CSR build (bucketed, zero global atomics; R4 showed direct random scatter is
// 7.7x write-amplified).  Per-edge atomic->store chains BATCHED x4 (int4 edge
// loads, 4 independent LDS-atomic+store chains per iteration) to hide ~120cyc
// LDS-atomic latency (R6: validated, build 193->174us).
// SpMM: 16-lane GROUP per row; lane owns 16B (8 bf16 features) of the row.
// Wave = 4 groups -> one gather instruction moves 4 x 256B = 1KB.
// pack[] loads are PLAIN (R6: nt-loads broke 8-edges-per-line spatial reuse,
// FETCH +70MB).  Output stores are NON-TEMPORAL (full-line, never re-read in
// dispatch; keeps L2 free for the gather table) -- via native ext_vector
// types (HIP_vector_type rejected by the builtin).

#define D_FEAT 128
#define D2     64          // feature pairs per row
#define SCAN_TILE 1024

#define PB 256             // partition/count blocks (= gridDim of those kernels)
#define PT 1024            // threads per partition/count block
#define RB_BITS 9          // rows per bucket = 512
#define ROWS_PER_BUCKET 512
#define COL_BITS 17        // N = 100000 < 2^17
#define COL_MASK ((1 << COL_BITS) - 1)

typedef unsigned int uintx4 __attribute__((ext_vector_type(4)));
typedef float        floatx4 __attribute__((ext_vector_type(4)));

__device__ __forceinline__ uint32_t f2bf(float f) {
    uint32_t u = __float_as_uint(f);
    return (u + 0x7FFFu + ((u >> 16) & 1u)) >> 16;   // RNE
}
__device__ __forceinline__ float bf_lo(uint32_t w) { return __uint_as_float(w << 16); }
__device__ __forceinline__ float bf_hi(uint32_t w) { return __uint_as_float(w & 0xFFFF0000u); }

// ------- fused: f32 -> bf16 table convert (float4) + coarse bucket count -------
__global__ __launch_bounds__(PT) void convert_count_kernel(const float4* __restrict__ xin,
                                                           uint2* __restrict__ xbf, int n4,
                                                           const int* __restrict__ row,
                                                           int* __restrict__ cnt,
                                                           int E, int nbuck) {
    __shared__ int hist[256];
    const int t = threadIdx.x;
    if (t < 256) hist[t] = 0;
    __syncthreads();
    const int stride = PB * PT;
    const int gid = blockIdx.x * PT + t;
    for (int i = gid; i < n4; i += stride) {
        float4 f = xin[i];
        xbf[i] = make_uint2(f2bf(f.x) | (f2bf(f.y) << 16),
                            f2bf(f.z) | (f2bf(f.w) << 16));
    }
    const int E4 = E >> 2;
    const int4* __restrict__ r4 = (const int4*)row;
    for (int i = gid; i < E4; i += stride) {
        int4 r = r4[i];
        atomicAdd(&hist[r.x >> RB_BITS], 1);
        atomicAdd(&hist[r.y >> RB_BITS], 1);
        atomicAdd(&hist[r.z >> RB_BITS], 1);
        atomicAdd(&hist[r.w >> RB_BITS], 1);
    }
    for (int i = (E4 << 2) + gid; i < E; i += stride)   // tail (E%4 != 0)
        atomicAdd(&hist[row[i] >> RB_BITS], 1);
    __syncthreads();
    if (t < nbuck) cnt[t * PB + blockIdx.x] = hist[t];
}

// ---------------- scan phase 1: per-tile exclusive scan + tile sums ----------------
__global__ __launch_bounds__(SCAN_TILE) void scan1_kernel(const int* __restrict__ counts,
                                                          int* __restrict__ excl,
                                                          int* __restrict__ tileSums, int n) {
    __shared__ int wsum[16];
    const int tid  = threadIdx.x;
    const int lane = tid & 63;
    const int wave = tid >> 6;
    const int i    = blockIdx.x * SCAN_TILE + tid;

    int v = (i < n) ? counts[i] : 0;
    int incl = v;
    #pragma unroll
    for (int off = 1; off < 64; off <<= 1) {
        int t = __shfl_up(incl, off, 64);
        if (lane >= off) incl += t;
    }
    if (lane == 63) wsum[wave] = incl;
    __syncthreads();
    if (wave == 0) {
        int s = (lane < 16) ? wsum[lane] : 0;
        #pragma unroll
        for (int off = 1; off < 16; off <<= 1) {
            int t = __shfl_up(s, off, 64);
            if (lane >= off) s += t;
        }
        if (lane < 16) wsum[lane] = s;
    }
    __syncthreads();
    int wbase = (wave == 0) ? 0 : wsum[wave - 1];
    if (i < n) excl[i] = wbase + (incl - v);
    if (tid == 0) tileSums[blockIdx.x] = wsum[15];
}

// ---------------- scan phase 2: single-wave shuffle scan of tile sums ----------------
__global__ __launch_bounds__(64) void scan2_kernel(const int* __restrict__ tileSums,
                                                   int* __restrict__ tileBase,
                                                   int* __restrict__ total_out, int nb) {
    const int lane = threadIdx.x;
    int v = (lane < nb) ? tileSums[lane] : 0;
    int incl = v;
    #pragma unroll
    for (int off = 1; off < 64; off <<= 1) {
        int t = __shfl_up(incl, off, 64);
        if (lane >= off) incl += t;
    }
    if (lane < nb) tileBase[lane] = incl - v;
    if (lane == nb - 1) *total_out = incl;
}

// ---------------- partition edges into coarse buckets (LDS cursors) ----------------
// 196 sequential write streams per block; 4 independent chains per iteration.
__global__ __launch_bounds__(PT) void partition_kernel(const int* __restrict__ row,
                                                       const int* __restrict__ col,
                                                       const float* __restrict__ val,
                                                       const int* __restrict__ cnt,
                                                       const int* __restrict__ tileBase,
                                                       int2* __restrict__ pack2,
                                                       int E, int nbuck) {
    __shared__ int cur[256];
    const int t = threadIdx.x;
    if (t < nbuck) {
        int idx = t * PB + blockIdx.x;
        cur[t] = cnt[idx] + tileBase[idx >> 10];
    }
    __syncthreads();
    const int stride = PB * PT;
    const int gid = blockIdx.x * PT + t;
    const int E4 = E >> 2;
    const int4*   __restrict__ r4 = (const int4*)row;
    const int4*   __restrict__ c4 = (const int4*)col;
    const float4* __restrict__ v4 = (const float4*)val;
    for (int i = gid; i < E4; i += stride) {
        int4   r = r4[i];
        int4   c = c4[i];
        float4 v = v4[i];
        int p0 = atomicAdd(&cur[r.x >> RB_BITS], 1);
        int p1 = atomicAdd(&cur[r.y >> RB_BITS], 1);
        int p2 = atomicAdd(&cur[r.z >> RB_BITS], 1);
        int p3 = atomicAdd(&cur[r.w >> RB_BITS], 1);
        pack2[p0] = make_int2(c.x | ((r.x & (ROWS_PER_BUCKET - 1)) << COL_BITS), __float_as_int(v.x));
        pack2[p1] = make_int2(c.y | ((r.y & (ROWS_PER_BUCKET - 1)) << COL_BITS), __float_as_int(v.y));
        pack2[p2] = make_int2(c.z | ((r.z & (ROWS_PER_BUCKET - 1)) << COL_BITS), __float_as_int(v.z));
        pack2[p3] = make_int2(c.w | ((r.w & (ROWS_PER_BUCKET - 1)) << COL_BITS), __float_as_int(v.w));
    }
    for (int i = (E4 << 2) + gid; i < E; i += stride) {  // tail
        int r = row[i];
        int pos = atomicAdd(&cur[r >> RB_BITS], 1);
        pack2[pos] = make_int2(col[i] | ((r & (ROWS_PER_BUCKET - 1)) << COL_BITS),
                               __float_as_int(val[i]));
    }
}

// ---------------- lean per-bucket fine sort (2 edges per int4 load) ----------------
__global__ __launch_bounds__(1024) void fine_sort_kernel(const int* __restrict__ cnt,
                                                         const int* __restrict__ tileBase,
                                                         const int2* __restrict__ pack2,
                                                         int2* __restrict__ pack,
                                                         int* __restrict__ offsets,
                                                         int E, int N, int nbuck) {
    __shared__ int hist[ROWS_PER_BUCKET];
    __shared__ int cur[ROWS_PER_BUCKET];
    __shared__ int wsum[8];
    const int b    = blockIdx.x;
    const int t    = threadIdx.x;
    const int wave = t >> 6;
    const int lane = t & 63;
    const int start = cnt[b << 8] + tileBase[b >> 2];
    const int end   = (b == nbuck - 1) ? E : (cnt[(b + 1) << 8] + tileBase[(b + 1) >> 2]);
    const int n = end - start;
    // int4 alignment: pack2+start is 16B-aligned iff start is even
    const int lead = (start & 1) & (n > 0 ? 1 : 0);
    const int base = start + lead;
    const int m  = n - lead;
    const int m2 = m >> 1;
    const int4* __restrict__ p4 = (const int4*)(pack2 + base);

    if (t < ROWS_PER_BUCKET) hist[t] = 0;
    __syncthreads();

    if (lead && t == 0) atomicAdd(&hist[((unsigned)pack2[start].x) >> COL_BITS], 1);
    for (int i = t; i < m2; i += 1024) {
        int4 w = p4[i];
        atomicAdd(&hist[((unsigned)w.x) >> COL_BITS], 1);
        atomicAdd(&hist[((unsigned)w.z) >> COL_BITS], 1);
    }
    if ((m & 1) && t == 0) atomicAdd(&hist[((unsigned)pack2[base + m - 1].x) >> COL_BITS], 1);
    __syncthreads();

    int v = 0, incl = 0;
    if (t < ROWS_PER_BUCKET) {           // waves 0..7, whole waves only
        v = hist[t];
        incl = v;
        #pragma unroll
        for (int off = 1; off < 64; off <<= 1) {
            int tv = __shfl_up(incl, off, 64);
            if (lane >= off) incl += tv;
        }
        if (lane == 63) wsum[wave] = incl;
    }
    __syncthreads();
    if (wave == 0) {                     // scan 8 wave sums
        int s = (lane < 8) ? wsum[lane] : 0;
        #pragma unroll
        for (int off = 1; off < 8; off <<= 1) {
            int tv = __shfl_up(s, off, 64);
            if (lane >= off) s += tv;
        }
        if (lane < 8) wsum[lane] = s;    // inclusive
    }
    __syncthreads();
    if (t < ROWS_PER_BUCKET) {
        int sbase = (wave == 0) ? 0 : wsum[wave - 1];
        int excl = sbase + incl - v;
        cur[t] = excl;
        int r = (b << RB_BITS) + t;
        if (r < N) offsets[r] = start + excl;
    }
    if (b == 0 && t == 0) offsets[N] = E;
    __syncthreads();

    if (lead && t == 0) {
        int2 w = pack2[start];
        int p = atomicAdd(&cur[((unsigned)w.x) >> COL_BITS], 1);
        pack[start + p] = make_int2(w.x & COL_MASK, w.y);
    }
    for (int i = t; i < m2; i += 1024) {
        int4 w = p4[i];
        int lr0 = ((unsigned)w.x) >> COL_BITS;
        int lr1 = ((unsigned)w.z) >> COL_BITS;
        int q0 = atomicAdd(&cur[lr0], 1);
        int q1 = atomicAdd(&cur[lr1], 1);
        pack[start + q0] = make_int2(w.x & COL_MASK, w.y);
        pack[start + q1] = make_int2(w.z & COL_MASK, w.w);
    }
    if ((m & 1) && t == 0) {
        int2 w = pack2[base + m - 1];
        int p = atomicAdd(&cur[((unsigned)w.x) >> COL_BITS], 1);
        pack[start + p] = make_int2(w.x & COL_MASK, w.y);
    }
}

// ---------------- fused SpMM (bf16 gather) + scalar scale + ELU ----------------
// Block = 256 threads = 16 groups of 16 lanes; GROUP owns one row.  Lane owns
// 16B (4 bf16-pair words = 8 features) of that row's accumulator.  A wave's
// gather instruction covers 4 groups x 256B = 1KB.  pack[] reads are
// group-uniform broadcasts (plain loads: 8 edges share each 64B line).
// Output stores NON-TEMPORAL: full-line streams, never re-read in-dispatch.
template <int OUT_BF16>
__global__ __launch_bounds__(256) void spmm_elu_kernel(
    const int* __restrict__ offsets, const int2* __restrict__ pack,
    const uint32_t* __restrict__ xin, void* __restrict__ xout,
    const float* __restrict__ scalars, int layer, int N) {
    const int tid = threadIdx.x;
    const int grp = tid >> 4;            // group within block (0..15)
    const int sub = tid & 15;            // 16B chunk within the source row
    const int r   = blockIdx.x * 16 + grp;

    int e = 0, end = 0;
    if (r < N) { e = offsets[r]; end = offsets[r + 1]; }

    const uint4* __restrict__ xin4 = (const uint4*)xin;       // row stride = 16 uint4
    const uint64_t* __restrict__ pk = (const uint64_t*)pack;  // 8B per edge

    float a[8];
    #pragma unroll
    for (int k = 0; k < 8; ++k) a[k] = 0.f;

    #define FMA8(W, V)                                                     \
        a[0] += (V) * bf_lo((W).x); a[1] += (V) * bf_hi((W).x);            \
        a[2] += (V) * bf_lo((W).y); a[3] += (V) * bf_hi((W).y);            \
        a[4] += (V) * bf_lo((W).z); a[5] += (V) * bf_hi((W).z);            \
        a[6] += (V) * bf_lo((W).w); a[7] += (V) * bf_hi((W).w);

    for (; e + 4 <= end; e += 4) {
        uint64_t q0 = pk[e];
        uint64_t q1 = pk[e + 1];
        uint64_t q2 = pk[e + 2];
        uint64_t q3 = pk[e + 3];
        uint4 w0 = xin4[(((uint32_t)q0) << 4) + sub];
        uint4 w1 = xin4[(((uint32_t)q1) << 4) + sub];
        uint4 w2 = xin4[(((uint32_t)q2) << 4) + sub];
        uint4 w3 = xin4[(((uint32_t)q3) << 4) + sub];
        FMA8(w0, __uint_as_float((uint32_t)(q0 >> 32)));
        FMA8(w1, __uint_as_float((uint32_t)(q1 >> 32)));
        FMA8(w2, __uint_as_float((uint32_t)(q2 >> 32)));
        FMA8(w3, __uint_as_float((uint32_t)(q3 >> 32)));
    }
    for (; e < end; ++e) {
        uint64_t q = pk[e];
        uint4 w = xin4[(((uint32_t)q) << 4) + sub];
        FMA8(w, __uint_as_float((uint32_t)(q >> 32)));
    }
    #undef FMA8

    const float s = scalars[layer];
    #pragma unroll
    for (int k = 0; k < 8; ++k) {
        float x = a[k] * s;
        a[k] = (x > 0.f) ? x : (expf(x) - 1.f);
    }

    if (r < N) {
        if (OUT_BF16) {
            uintx4 o;
            o.x = f2bf(a[0]) | (f2bf(a[1]) << 16);
            o.y = f2bf(a[2]) | (f2bf(a[3]) << 16);
            o.z = f2bf(a[4]) | (f2bf(a[5]) << 16);
            o.w = f2bf(a[6]) | (f2bf(a[7]) << 16);
            __builtin_nontemporal_store(o, (uintx4*)xout + (size_t)r * 16 + sub);
        } else {
            floatx4 o0 = {a[0], a[1], a[2], a[3]};
            floatx4 o1 = {a[4], a[5], a[6], a[7]};
            __builtin_nontemporal_store(o0, (floatx4*)xout + (size_t)r * 32 + sub * 2);
            __builtin_nontemporal_store(o1, (floatx4*)xout + (size_t)r * 32 + sub * 2 + 1);
        }
    }
}

extern "C" void kernel_launch(void* const* d_in, const int* in_sizes, int n_in,
                              void* d_out, int out_size, void* d_ws, size_t ws_size,
                              hipStream_t stream) {
    const float* x         = (const float*)d_in[0];
    const int*   edge_row  = (const int*)d_in[1];
    const int*   edge_col  = (const int*)d_in[2];
    const float* edge_vals = (const float*)d_in[3];
    const float* scalars   = (const float*)d_in[4];

    const int N = in_sizes[0] / D_FEAT;                      // 100000
    const int E = in_sizes[1];                               // 3200000
    const int nbuck = (N + ROWS_PER_BUCKET - 1) >> RB_BITS;  // 196
    const int M = nbuck * PB;                                // 50176
    const int NB = (M + SCAN_TILE - 1) / SCAN_TILE;          // 49

    // ---- workspace bump allocator (256B aligned) ----
    char*  ws  = (char*)d_ws;
    size_t off = 0;
    auto alloc = [&](size_t bytes) -> void* {
        off = (off + 255) & ~(size_t)255;
        void* p = ws + off;
        off += bytes;
        return p;
    };
    int*      offsets  = (int*)alloc((size_t)(N + 1) * sizeof(int));
    int*      cnt      = (int*)alloc((size_t)(M + 1) * sizeof(int));
    int*      tileSums = (int*)alloc((size_t)NB * sizeof(int));
    int*      tileBase = (int*)alloc((size_t)NB * sizeof(int));
    int2*     pack2    = (int2*)alloc((size_t)E * sizeof(int2));
    int2*     pack     = (int2*)alloc((size_t)E * sizeof(int2));
    uint32_t* xbf      = (uint32_t*)alloc((size_t)N * D2 * sizeof(uint32_t));
    uint32_t* hbf      = (uint32_t*)pack2;   // alias: pack2 dead after fine_sort
    (void)ws_size;

    // ---- bf16 table + CSR build (no global atomics) ----
    convert_count_kernel<<<PB, PT, 0, stream>>>((const float4*)x, (uint2*)xbf, N * D2 / 2,
                                                edge_row, cnt, E, nbuck);
    scan1_kernel<<<NB, SCAN_TILE, 0, stream>>>(cnt, cnt, tileSums, M);
    scan2_kernel<<<1, 64, 0, stream>>>(tileSums, tileBase, cnt + M, NB);
    partition_kernel<<<PB, PT, 0, stream>>>(edge_row, edge_col, edge_vals, cnt, tileBase,
                                            pack2, E, nbuck);
    fine_sort_kernel<<<nbuck, 1024, 0, stream>>>(cnt, tileBase, pack2, pack, offsets, E, N, nbuck);

    // ---- layer 1: xbf -> hbf (bf16), layer 2: hbf -> d_out (f32) ----
    const int nblk = (N + 15) / 16;
    spmm_elu_kernel<1><<<nblk, 256, 0, stream>>>(offsets, pack, xbf, hbf, scalars, 0, N);
    spmm_elu_kernel<0><<<nblk, 256, 0, stream>>>(offsets, pack, hbf, (void*)d_out, scalars, 1, N);
}

// Round 9
// 412.107 us; speedup vs baseline: 1.1204x; 1.0408x over previous
//
#include <hip/hip_runtime.h>
#include <math.h>
#include <stdint.h>

// ScalarSGC: 2 layers of  x <- elu( scalars[l] * (A @ x) )
// R9 = R1 restoration (best measured: 412.8us) + int4-batched edge loads in
// coarse_count/partition (R6-validated: 4 independent LDS-atomic->store
// chains per iteration hide ~120cyc LDS-atomic latency).
// CSR built per call with ZERO global atomics: coarse LDS count -> 3-phase
// scan -> LDS-cursor partition (196 sequential write streams per block) ->
// per-bucket fine sort with full-bucket LDS edge cache.
// SpMM: wave-per-row, 4 lane-groups of 16 lanes each gather a FULL 256B
// source row via global_load_dwordx4 (1KB/instruction = 4 edges),
// scalarized pack reads, fused scale + ELU.  Pinned at ~3.9TB/s L2-miss-path
// (BW-bound: lower-VALU variants are NOT faster).  fp8 table rejected:
// error amplification -> absmax ~1.6 > 0.5 tolerance.

#define D_FEAT 128
#define D2     64          // feature pairs per row
#define SCAN_TILE 1024

#define PB 256             // partition/count blocks
#define PT 1024            // threads per partition/count block
#define RB_BITS 9          // rows per bucket = 512
#define ROWS_PER_BUCKET 512
#define COL_BITS 17        // N = 100000 < 2^17
#define CACHE_CAP 17152    // LDS edge cache entries (mean 16384, +6 sigma)

__device__ __forceinline__ uint32_t f2bf(float f) {
    uint32_t u = __float_as_uint(f);
    return (u + 0x7FFFu + ((u >> 16) & 1u)) >> 16;   // RNE
}
__device__ __forceinline__ float bf_lo(uint32_t w) { return __uint_as_float(w << 16); }
__device__ __forceinline__ float bf_hi(uint32_t w) { return __uint_as_float(w & 0xFFFF0000u); }

// ---------------- f32 -> bf16 conversion (2 elems/thread) ----------------
__global__ void convert_kernel(const float2* __restrict__ xin, uint32_t* __restrict__ xbf, int n2) {
    int i = blockIdx.x * blockDim.x + threadIdx.x;
    if (i < n2) {
        float2 f = xin[i];
        xbf[i] = f2bf(f.x) | (f2bf(f.y) << 16);
    }
}

// ---------------- phase 1: coarse per-(bucket,block) counts, LDS only ----------------
__global__ __launch_bounds__(PT) void coarse_count_kernel(const int* __restrict__ row,
                                                          int* __restrict__ cnt,
                                                          int E, int nbuck) {
    __shared__ int hist[256];
    const int t = threadIdx.x;
    if (t < 256) hist[t] = 0;
    __syncthreads();
    const int stride = PB * PT;
    const int gid = blockIdx.x * PT + t;
    const int E4 = E >> 2;
    const int4* __restrict__ r4 = (const int4*)row;
    for (int i = gid; i < E4; i += stride) {
        int4 r = r4[i];
        atomicAdd(&hist[r.x >> RB_BITS], 1);
        atomicAdd(&hist[r.y >> RB_BITS], 1);
        atomicAdd(&hist[r.z >> RB_BITS], 1);
        atomicAdd(&hist[r.w >> RB_BITS], 1);
    }
    for (int i = (E4 << 2) + gid; i < E; i += stride)   // tail (E%4 != 0)
        atomicAdd(&hist[row[i] >> RB_BITS], 1);
    __syncthreads();
    if (t < nbuck) cnt[t * PB + blockIdx.x] = hist[t];
}

// ---------------- scan phase 1: per-tile exclusive scan + tile sums ----------------
__global__ __launch_bounds__(SCAN_TILE) void scan1_kernel(const int* __restrict__ counts,
                                                          int* __restrict__ excl,
                                                          int* __restrict__ tileSums, int n) {
    __shared__ int wsum[16];
    const int tid  = threadIdx.x;
    const int lane = tid & 63;
    const int wave = tid >> 6;
    const int i    = blockIdx.x * SCAN_TILE + tid;

    int v = (i < n) ? counts[i] : 0;
    int incl = v;
    #pragma unroll
    for (int off = 1; off < 64; off <<= 1) {
        int t = __shfl_up(incl, off, 64);
        if (lane >= off) incl += t;
    }
    if (lane == 63) wsum[wave] = incl;
    __syncthreads();
    if (wave == 0) {
        int s = (lane < 16) ? wsum[lane] : 0;
        #pragma unroll
        for (int off = 1; off < 16; off <<= 1) {
            int t = __shfl_up(s, off, 64);
            if (lane >= off) s += t;
        }
        if (lane < 16) wsum[lane] = s;
    }
    __syncthreads();
    int wbase = (wave == 0) ? 0 : wsum[wave - 1];
    if (i < n) excl[i] = wbase + (incl - v);
    if (tid == 0) tileSums[blockIdx.x] = wsum[15];
}

// ---------------- scan phase 2: scan tile sums (single block) ----------------
__global__ __launch_bounds__(1024) void scan2_kernel(const int* __restrict__ tileSums,
                                                     int* __restrict__ tileBase,
                                                     int* __restrict__ total_out, int nb) {
    __shared__ int buf[1024];
    const int tid = threadIdx.x;
    int v = (tid < nb) ? tileSums[tid] : 0;
    buf[tid] = v;
    __syncthreads();
    #pragma unroll
    for (int off = 1; off < 1024; off <<= 1) {
        int t = (tid >= off) ? buf[tid - off] : 0;
        __syncthreads();
        buf[tid] += t;
        __syncthreads();
    }
    if (tid < nb) tileBase[tid] = buf[tid] - v;
    if (tid == nb - 1) *total_out = buf[tid];
}

// ---------------- phase 2: partition edges into coarse buckets (LDS cursors) ------
// 196 sequential write streams per block; 4 independent chains per iteration.
__global__ __launch_bounds__(PT) void partition_kernel(const int* __restrict__ row,
                                                       const int* __restrict__ col,
                                                       const float* __restrict__ val,
                                                       const int* __restrict__ cnt,
                                                       const int* __restrict__ tileBase,
                                                       int2* __restrict__ pack2,
                                                       int E, int nbuck) {
    __shared__ int cur[256];
    const int t = threadIdx.x;
    if (t < nbuck) {
        int idx = t * PB + blockIdx.x;
        cur[t] = cnt[idx] + tileBase[idx >> 10];
    }
    __syncthreads();
    const int stride = PB * PT;
    const int gid = blockIdx.x * PT + t;
    const int E4 = E >> 2;
    const int4*   __restrict__ r4 = (const int4*)row;
    const int4*   __restrict__ c4 = (const int4*)col;
    const float4* __restrict__ v4 = (const float4*)val;
    for (int i = gid; i < E4; i += stride) {
        int4   r = r4[i];
        int4   c = c4[i];
        float4 v = v4[i];
        int p0 = atomicAdd(&cur[r.x >> RB_BITS], 1);
        int p1 = atomicAdd(&cur[r.y >> RB_BITS], 1);
        int p2 = atomicAdd(&cur[r.z >> RB_BITS], 1);
        int p3 = atomicAdd(&cur[r.w >> RB_BITS], 1);
        pack2[p0] = make_int2(c.x | ((r.x & (ROWS_PER_BUCKET - 1)) << COL_BITS), __float_as_int(v.x));
        pack2[p1] = make_int2(c.y | ((r.y & (ROWS_PER_BUCKET - 1)) << COL_BITS), __float_as_int(v.y));
        pack2[p2] = make_int2(c.z | ((r.z & (ROWS_PER_BUCKET - 1)) << COL_BITS), __float_as_int(v.z));
        pack2[p3] = make_int2(c.w | ((r.w & (ROWS_PER_BUCKET - 1)) << COL_BITS), __float_as_int(v.w));
    }
    for (int i = (E4 << 2) + gid; i < E; i += stride) {  // tail
        int r = row[i];
        int pos = atomicAdd(&cur[r >> RB_BITS], 1);
        pack2[pos] = make_int2(col[i] | ((r & (ROWS_PER_BUCKET - 1)) << COL_BITS),
                               __float_as_int(val[i]));
    }
}

// ---------------- phase 3: per-bucket fine sort, LDS edge cache ----------------
__global__ __launch_bounds__(1024) void fine_sort_kernel(const int* __restrict__ cnt,
                                                         const int* __restrict__ tileBase,
                                                         const int2* __restrict__ pack2,
                                                         int2* __restrict__ pack,
                                                         int* __restrict__ offsets,
                                                         int E, int N, int nbuck) {
    extern __shared__ int2 ecache[];                  // CACHE_CAP entries
    __shared__ int buf[1024];
    __shared__ int cur[ROWS_PER_BUCKET];
    const int b = blockIdx.x;
    const int t = threadIdx.x;
    const int start = cnt[b << 8] + tileBase[b >> 2];
    const int end   = (b == nbuck - 1) ? E : (cnt[(b + 1) << 8] + tileBase[(b + 1) >> 2]);
    const int n  = end - start;
    const int nc = (n < CACHE_CAP) ? n : CACHE_CAP;

    for (int i = t; i < nc; i += 1024) ecache[i] = pack2[start + i];
    buf[t] = 0;
    __syncthreads();

    for (int i = t; i < n; i += 1024) {
        int key = (i < nc) ? ecache[i].x : pack2[start + i].x;
        atomicAdd(&buf[((unsigned)key) >> COL_BITS], 1);
    }
    __syncthreads();

    int v = buf[t];
    for (int off = 1; off < 1024; off <<= 1) {
        int tv = (t >= off) ? buf[t - off] : 0;
        __syncthreads();
        buf[t] += tv;
        __syncthreads();
    }
    int excl = buf[t] - v;
    if (t < ROWS_PER_BUCKET) {
        int r = (b << RB_BITS) + t;
        if (r < N) offsets[r] = start + excl;
        cur[t] = excl;
    }
    if (b == 0 && t == 0) offsets[N] = E;
    __syncthreads();

    for (int i = t; i < n; i += 1024) {
        int2 w = (i < nc) ? ecache[i] : pack2[start + i];
        int lr = ((unsigned)w.x) >> COL_BITS;
        int p = atomicAdd(&cur[lr], 1);               // LDS atomic
        pack[start + p] = make_int2(w.x & ((1 << COL_BITS) - 1), w.y);
    }
}

// ---------------- fused SpMM (bf16 gather) + scalar scale + ELU ----------------
// Block = 256 threads = 4 waves; wave owns one row.  The wave's 64 lanes split
// into 4 groups of 16: group g handles edge slot g of each 4-edge batch, lane
// loads 16B of the 256B source row via global_load_dwordx4 (1KB/instruction).
// Partial sums merged with two shfl_xor rounds at row end.
template <int OUT_BF16>
__global__ __launch_bounds__(256) void spmm_elu_kernel(
    const int* __restrict__ offsets, const int2* __restrict__ pack,
    const uint32_t* __restrict__ xin, void* __restrict__ xout,
    const float* __restrict__ scalars, int layer, int N) {
    const int wave = threadIdx.x >> 6;
    const int lane = threadIdx.x & 63;
    const int g    = lane >> 4;          // edge slot within a 4-edge batch
    const int sub  = lane & 15;          // 16B chunk within the source row
    const int r    = blockIdx.x * 4 + wave;
    if (r >= N) return;

    // wave-uniform -> SGPR so pack reads scalarize and the loop runs on SALU
    int e         = __builtin_amdgcn_readfirstlane(offsets[r]);
    const int end = __builtin_amdgcn_readfirstlane(offsets[r + 1]);

    const uint4* __restrict__ xin4 = (const uint4*)xin;   // row stride = 16 uint4

    float a[8];
    #pragma unroll
    for (int k = 0; k < 8; ++k) a[k] = 0.f;

    #define SEL4(PK, CO, VO)                                               \
        {                                                                  \
            int2 p0 = (PK)[0], p1 = (PK)[1], p2 = (PK)[2], p3 = (PK)[3];   \
            int cA = (g & 1) ? p1.x : p0.x, cB = (g & 1) ? p3.x : p2.x;    \
            int vA = (g & 1) ? p1.y : p0.y, vB = (g & 1) ? p3.y : p2.y;    \
            CO = (g & 2) ? cB : cA;                                        \
            VO = __int_as_float((g & 2) ? vB : vA);                        \
        }

    #define FMA8(W, V)                                                     \
        a[0] += (V) * bf_lo((W).x); a[1] += (V) * bf_hi((W).x);            \
        a[2] += (V) * bf_lo((W).y); a[3] += (V) * bf_hi((W).y);            \
        a[4] += (V) * bf_lo((W).z); a[5] += (V) * bf_hi((W).z);            \
        a[6] += (V) * bf_lo((W).w); a[7] += (V) * bf_hi((W).w);

    for (; e + 16 <= end; e += 16) {
        int c0, c1, c2, c3; float v0, v1, v2, v3;
        SEL4(pack + e,      c0, v0);
        SEL4(pack + e + 4,  c1, v1);
        SEL4(pack + e + 8,  c2, v2);
        SEL4(pack + e + 12, c3, v3);
        uint4 w0 = xin4[(((uint32_t)c0) << 4) + sub];
        uint4 w1 = xin4[(((uint32_t)c1) << 4) + sub];
        uint4 w2 = xin4[(((uint32_t)c2) << 4) + sub];
        uint4 w3 = xin4[(((uint32_t)c3) << 4) + sub];
        FMA8(w0, v0); FMA8(w1, v1); FMA8(w2, v2); FMA8(w3, v3);
    }
    for (; e + 4 <= end; e += 4) {
        int c0; float v0;
        SEL4(pack + e, c0, v0);
        uint4 w0 = xin4[(((uint32_t)c0) << 4) + sub];
        FMA8(w0, v0);
    }
    if (e < end) {                       // 1..3 leftover edges, pad with val=0
        const int rem = end - e;
        int2 pl = pack[end - 1];
        int2 p0 = pack[e];
        int2 p1 = (rem > 1) ? pack[e + 1] : make_int2(pl.x, 0);
        int2 p2 = (rem > 2) ? pack[e + 2] : make_int2(pl.x, 0);
        int2 p3 = make_int2(pl.x, 0);
        int cA = (g & 1) ? p1.x : p0.x, cB = (g & 1) ? p3.x : p2.x;
        int vA = (g & 1) ? p1.y : p0.y, vB = (g & 1) ? p3.y : p2.y;
        int c0 = (g & 2) ? cB : cA;
        float v0 = __int_as_float((g & 2) ? vB : vA);
        uint4 w0 = xin4[(((uint32_t)c0) << 4) + sub];
        FMA8(w0, v0);
    }
    #undef SEL4
    #undef FMA8

    // merge the 4 lane-group partials (same features live at same 'sub')
    #pragma unroll
    for (int off = 16; off <= 32; off <<= 1) {
        #pragma unroll
        for (int k = 0; k < 8; ++k) a[k] += __shfl_xor(a[k], off, 64);
    }

    const float s = scalars[layer];
    #pragma unroll
    for (int k = 0; k < 8; ++k) {
        float x = a[k] * s;
        a[k] = (x > 0.f) ? x : (expf(x) - 1.f);
    }

    if (OUT_BF16) {
        if (g == 0) {
            uint4 o;
            o.x = f2bf(a[0]) | (f2bf(a[1]) << 16);
            o.y = f2bf(a[2]) | (f2bf(a[3]) << 16);
            o.z = f2bf(a[4]) | (f2bf(a[5]) << 16);
            o.w = f2bf(a[6]) | (f2bf(a[7]) << 16);
            ((uint4*)xout)[(size_t)r * 16 + sub] = o;
        }
    } else {
        if (g == 0)
            ((float4*)xout)[(size_t)r * 32 + sub * 2]     = make_float4(a[0], a[1], a[2], a[3]);
        else if (g == 1)
            ((float4*)xout)[(size_t)r * 32 + sub * 2 + 1] = make_float4(a[4], a[5], a[6], a[7]);
    }
}

extern "C" void kernel_launch(void* const* d_in, const int* in_sizes, int n_in,
                              void* d_out, int out_size, void* d_ws, size_t ws_size,
                              hipStream_t stream) {
    const float* x         = (const float*)d_in[0];
    const int*   edge_row  = (const int*)d_in[1];
    const int*   edge_col  = (const int*)d_in[2];
    const float* edge_vals = (const float*)d_in[3];
    const float* scalars   = (const float*)d_in[4];

    const int N = in_sizes[0] / D_FEAT;                      // 100000
    const int E = in_sizes[1];                               // 3200000
    const int nbuck = (N + ROWS_PER_BUCKET - 1) >> RB_BITS;  // 196
    const int M = nbuck * PB;                                // 50176
    const int NB = (M + SCAN_TILE - 1) / SCAN_TILE;          // 49

    // ---- workspace bump allocator (256B aligned) ----
    char*  ws  = (char*)d_ws;
    size_t off = 0;
    auto alloc = [&](size_t bytes) -> void* {
        off = (off + 255) & ~(size_t)255;
        void* p = ws + off;
        off += bytes;
        return p;
    };
    int*      offsets  = (int*)alloc((size_t)(N + 1) * sizeof(int));
    int*      cnt      = (int*)alloc((size_t)(M + 1) * sizeof(int));
    int*      tileSums = (int*)alloc((size_t)NB * sizeof(int));
    int*      tileBase = (int*)alloc((size_t)NB * sizeof(int));
    int2*     pack2    = (int2*)alloc((size_t)E * sizeof(int2));
    int2*     pack     = (int2*)alloc((size_t)E * sizeof(int2));
    uint32_t* xbf      = (uint32_t*)alloc((size_t)N * D2 * sizeof(uint32_t));
    uint32_t* hbf      = (uint32_t*)pack2;   // alias: pack2 dead after fine_sort
    (void)ws_size;

    // ---- bf16 table + CSR build (no global atomics) ----
    convert_kernel<<<(N * D2 + 255) / 256, 256, 0, stream>>>((const float2*)x, xbf, N * D2);
    coarse_count_kernel<<<PB, PT, 0, stream>>>(edge_row, cnt, E, nbuck);
    scan1_kernel<<<NB, SCAN_TILE, 0, stream>>>(cnt, cnt, tileSums, M);
    scan2_kernel<<<1, 1024, 0, stream>>>(tileSums, tileBase, cnt + M, NB);
    partition_kernel<<<PB, PT, 0, stream>>>(edge_row, edge_col, edge_vals, cnt, tileBase,
                                            pack2, E, nbuck);
    fine_sort_kernel<<<nbuck, 1024, (size_t)CACHE_CAP * sizeof(int2), stream>>>(
        cnt, tileBase, pack2, pack, offsets, E, N, nbuck);

    // ---- layer 1: xbf -> hbf (bf16), layer 2: hbf -> d_out (f32) ----
    const int nblk = (N + 3) / 4;
    spmm_elu_kernel<1><<<nblk, 256, 0, stream>>>(offsets, pack, xbf, hbf, scalars, 0, N);
    spmm_elu_kernel<0><<<nblk, 256, 0, stream>>>(offsets, pack, hbf, (void*)d_out, scalars, 1, N);
}